// Round 2
// baseline (927.834 us; speedup 1.0000x reference)
//
#include <hip/hip_runtime.h>
#include <hip/hip_bf16.h>
#include <cstdint>

typedef __attribute__((ext_vector_type(4))) float f32x4;
typedef __attribute__((ext_vector_type(8))) short bf16x8;

__device__ inline unsigned short f2bf(float f) {
    union { float f; unsigned u; } v; v.f = f;
    unsigned r = v.u + 0x7FFFu + ((v.u >> 16) & 1u);
    return (unsigned short)(r >> 16);
}
__device__ inline float bf2f(unsigned short h) {
    union { unsigned u; float f; } v; v.u = ((unsigned)h) << 16;
    return v.f;
}

// ---------------------------------------------------------------- prep
__global__ void prep_kernel(
    const float* __restrict__ We,
    const float* __restrict__ Wul, const float* __restrict__ Wau, const float* __restrict__ WVu,
    const float* __restrict__ Wvl, const float* __restrict__ Wav, const float* __restrict__ WVv,
    const float* __restrict__ Wwu, const float* __restrict__ Wwv,
    const float* __restrict__ bul, const float* __restrict__ bau, const float* __restrict__ bVu,
    const float* __restrict__ bvl, const float* __restrict__ bav, const float* __restrict__ bVv,
    unsigned short* __restrict__ WeT, unsigned short* __restrict__ WuT, unsigned short* __restrict__ WvT,
    unsigned short* __restrict__ WwuT, unsigned short* __restrict__ WwvT,
    float* __restrict__ bcu, float* __restrict__ bcv,
    int* __restrict__ cnt_u, int NU, int* __restrict__ cnt_v, int NV)
{
    int tid0 = blockIdx.x * blockDim.x + threadIdx.x;
    int stride = gridDim.x * blockDim.x;
    for (int i = tid0; i < 64 * 64; i += stride) { int c = i >> 6, k = i & 63; WeT[i] = f2bf(We[k * 64 + c]); }
    for (int i = tid0; i < 224 * 64; i += stride) {
        int c = i >> 6, k = i & 63;
        float v = (c < 64) ? Wul[k * 64 + c] : (c < 192) ? Wau[k * 128 + (c - 64)] : WVu[k * 32 + (c - 192)];
        WuT[i] = f2bf(v);
    }
    for (int i = tid0; i < 224 * 64; i += stride) {
        int c = i >> 6, k = i & 63;
        float v = (c < 64) ? Wvl[k * 64 + c] : (c < 192) ? Wav[k * 128 + (c - 64)] : WVv[k * 32 + (c - 192)];
        WvT[i] = f2bf(v);
    }
    for (int i = tid0; i < 32 * 128; i += stride) { int c = i >> 7, k = i & 127; WwuT[i] = f2bf(Wwu[k * 32 + c]); }
    for (int i = tid0; i < 32 * 128; i += stride) { int c = i >> 7, k = i & 127; WwvT[i] = f2bf(Wwv[k * 32 + c]); }
    for (int i = tid0; i < 224; i += stride) {
        bcu[i] = (i < 64) ? bul[i] : (i < 192) ? bau[i - 64] : bVu[i - 192];
        bcv[i] = (i < 64) ? bvl[i] : (i < 192) ? bav[i - 64] : bVv[i - 192];
    }
    for (int i = tid0; i < NU; i += stride) cnt_u[i] = 0;
    for (int i = tid0; i < NV; i += stride) cnt_v[i] = 0;
}

// ---------------------------------------------------------------- CSR build
__global__ void count_kernel(const int* __restrict__ dst, int E,
                             int* __restrict__ cnt, int* __restrict__ slot)
{
    int i = blockIdx.x * blockDim.x + threadIdx.x;
    int stride = gridDim.x * blockDim.x;
    for (; i < E; i += stride) slot[i] = atomicAdd(&cnt[dst[i]], 1);
}

__global__ __launch_bounds__(1024) void scan_kernel(const int* __restrict__ cnt, int n,
                                                    int* __restrict__ off)
{
    __shared__ int ts[1024];
    int t = threadIdx.x;
    int C = (n + 1023) >> 10;
    int b = t * C;
    int e = b + C; if (e > n) e = n; if (b > n) b = n;
    int s = 0;
    for (int i = b; i < e; ++i) s += cnt[i];
    ts[t] = s;
    __syncthreads();
    for (int d = 1; d < 1024; d <<= 1) {
        int add = (t >= d) ? ts[t - d] : 0;
        __syncthreads();
        ts[t] += add;
        __syncthreads();
    }
    int run = ts[t] - s;  // exclusive prefix for this chunk
    for (int i = b; i < e; ++i) { off[i] = run; run += cnt[i]; }
    if (t == 1023) off[n] = ts[1023];
}

__global__ void scatter_kernel(const int* __restrict__ dst, const int* __restrict__ slot,
                               const int* __restrict__ off, int E, int* __restrict__ list)
{
    int i = blockIdx.x * blockDim.x + threadIdx.x;
    int stride = gridDim.x * blockDim.x;
    for (; i < E; i += stride) list[off[dst[i]] + slot[i]] = i;
}

// ---------------------------------------------------------------- node pre:
// [64 nodes/block] feat@[Wl|Wa|WV] (K=64, N=224) -> he(bf16), att(bf16), outV(f32)
__global__ __launch_bounds__(256) void node_pre_kernel(
    const float* __restrict__ feat, int N,
    const unsigned short* __restrict__ WT,   // [224][64] bf16 (c-major)
    const float* __restrict__ bcat,          // [224]
    unsigned short* __restrict__ he,         // [N][64]  bf16
    unsigned short* __restrict__ att,        // [N][128] bf16
    float* __restrict__ outV)                // out rows stride 64, cols 0..31
{
    __shared__ unsigned short lA[64 * 64];
    __shared__ unsigned short lW[224 * 64];
    int tid = threadIdx.x;
    int n0 = blockIdx.x * 64;

    const uint4* wsrc = (const uint4*)WT;
    for (int i = tid; i < 224 * 8; i += 256) {
        int r = i >> 3, ch = i & 7;
        *(uint4*)&lW[r * 64 + ((ch ^ (r & 7)) << 3)] = wsrc[i];
    }
    #pragma unroll
    for (int j = 0; j < 4; ++j) {
        int fi = j * 1024 + tid * 4;
        int r = fi >> 6, k = fi & 63;
        int n = n0 + r;
        float4 v = make_float4(0.f, 0.f, 0.f, 0.f);
        if (n < N) v = *(const float4*)&feat[(size_t)n * 64 + k];
        uint2 pk;
        pk.x = (unsigned)f2bf(v.x) | ((unsigned)f2bf(v.y) << 16);
        pk.y = (unsigned)f2bf(v.z) | ((unsigned)f2bf(v.w) << 16);
        *(uint2*)&lA[r * 64 + (((k >> 3) ^ (r & 7)) << 3) + (k & 7)] = pk;
    }
    __syncthreads();

    int wv = tid >> 6, lane = tid & 63;
    int r0 = wv * 16;
    int lrow = lane & 15, lkg = lane >> 4;
    int rr = r0 + lrow;

    bf16x8 a[2];
    #pragma unroll
    for (int h = 0; h < 2; ++h) {
        int ch = h * 4 + lkg;
        a[h] = *(const bf16x8*)&lA[rr * 64 + ((ch ^ (rr & 7)) << 3)];
    }
    f32x4 acc[14];
    #pragma unroll
    for (int t = 0; t < 14; ++t) acc[t] = (f32x4){0.f, 0.f, 0.f, 0.f};
    #pragma unroll
    for (int t = 0; t < 14; ++t) {
        int row = t * 16 + lrow;
        #pragma unroll
        for (int h = 0; h < 2; ++h) {
            int ch = h * 4 + lkg;
            bf16x8 b = *(const bf16x8*)&lW[row * 64 + ((ch ^ (row & 7)) << 3)];
            acc[t] = __builtin_amdgcn_mfma_f32_16x16x32_bf16(a[h], b, acc[t], 0, 0, 0);
        }
    }
    #pragma unroll
    for (int t = 0; t < 14; ++t) {
        #pragma unroll
        for (int q = 0; q < 4; ++q) {
            int n = n0 + r0 + lkg * 4 + q;
            if (n >= N) continue;
            int c = t * 16 + lrow;
            float v = acc[t][q] + bcat[c];
            if (t < 4)       he[(size_t)n * 64 + c] = f2bf(v);
            else if (t < 12) att[(size_t)n * 128 + (c - 64)] = f2bf(v);
            else             outV[(size_t)n * 64 + (c - 192)] = v;
        }
    }
}

// ---------------------------------------------------------------- edge:
// [64 edges/block] out_he = e@We + be + he_src[src] + he_dst[dst];
// w[e] = exp(<[src_feat[src]|e], att_dst[dst]>)   (no atomics)
__global__ __launch_bounds__(256) void edge_kernel(
    const float* __restrict__ efeat, int E,
    const int* __restrict__ src, const int* __restrict__ dst,
    const float* __restrict__ src_feat,
    const unsigned short* __restrict__ he_src, const unsigned short* __restrict__ he_dst,
    const unsigned short* __restrict__ att_dst,
    const unsigned short* __restrict__ WeT,
    const float* __restrict__ be,
    float* __restrict__ out_he,
    float* __restrict__ w_out)
{
    // 16 KB total: lA(8K)+lW(8K) during MFMA, reused as sAcc(16K f32) after
    __shared__ __align__(16) char smem[16384];
    unsigned short* lA = (unsigned short*)smem;
    unsigned short* lW = (unsigned short*)(smem + 8192);
    float* sAcc = (float*)smem;

    int tid = threadIdx.x;
    int e0 = blockIdx.x * 64;

    const uint4* wsrc = (const uint4*)WeT;
    for (int i = tid; i < 512; i += 256) {
        int r = i >> 3, ch = i & 7;
        *(uint4*)&lW[r * 64 + ((ch ^ (r & 7)) << 3)] = wsrc[i];
    }
    #pragma unroll
    for (int j = 0; j < 4; ++j) {
        int fi = j * 1024 + tid * 4;
        int r = fi >> 6, k = fi & 63;
        int e = e0 + r;
        float4 v = make_float4(0.f, 0.f, 0.f, 0.f);
        if (e < E) v = *(const float4*)&efeat[(size_t)e * 64 + k];
        uint2 pk;
        pk.x = (unsigned)f2bf(v.x) | ((unsigned)f2bf(v.y) << 16);
        pk.y = (unsigned)f2bf(v.z) | ((unsigned)f2bf(v.w) << 16);
        *(uint2*)&lA[r * 64 + (((k >> 3) ^ (r & 7)) << 3) + (k & 7)] = pk;
    }
    __syncthreads();

    int wv = tid >> 6, lane = tid & 63;
    int r0 = wv * 16;
    int lrow = lane & 15, lkg = lane >> 4;
    int rr = r0 + lrow;

    bf16x8 a[2];
    #pragma unroll
    for (int h = 0; h < 2; ++h) {
        int ch = h * 4 + lkg;
        a[h] = *(const bf16x8*)&lA[rr * 64 + ((ch ^ (rr & 7)) << 3)];
    }
    f32x4 acc[4];
    #pragma unroll
    for (int t = 0; t < 4; ++t) acc[t] = (f32x4){0.f, 0.f, 0.f, 0.f};
    #pragma unroll
    for (int t = 0; t < 4; ++t) {
        int row = t * 16 + lrow;
        #pragma unroll
        for (int h = 0; h < 2; ++h) {
            int ch = h * 4 + lkg;
            bf16x8 b = *(const bf16x8*)&lW[row * 64 + ((ch ^ (row & 7)) << 3)];
            acc[t] = __builtin_amdgcn_mfma_f32_16x16x32_bf16(a[h], b, acc[t], 0, 0, 0);
        }
    }
    __syncthreads();   // all waves done reading lA/lW before overwriting with sAcc
    #pragma unroll
    for (int t = 0; t < 4; ++t) {
        #pragma unroll
        for (int q = 0; q < 4; ++q) {
            int r = r0 + lkg * 4 + q;
            int c = t * 16 + lrow;
            sAcc[r * 64 + c] = acc[t][q] + be[c];
        }
    }
    __syncthreads();

    // score + hf phase: 1 edge per iteration, fully coalesced row accesses
    for (int q2 = 0; q2 < 16; ++q2) {
        int rloc = wv * 16 + q2;
        int e = e0 + rloc;
        if (e >= E) break;
        int si = src[e], di = dst[e];
        int c = lane;
        float a1 = src_feat[(size_t)si * 64 + c];
        float t1 = bf2f(att_dst[(size_t)di * 128 + c]);
        float t2 = bf2f(att_dst[(size_t)di * 128 + 64 + c]);
        float a2 = efeat[(size_t)e * 64 + c];
        float hs = bf2f(he_src[(size_t)si * 64 + c]);
        float hd = bf2f(he_dst[(size_t)di * 64 + c]);
        out_he[(size_t)e * 64 + c] = sAcc[rloc * 64 + c] + hs + hd;
        float p = a1 * t1 + a2 * t2;
        #pragma unroll
        for (int off = 32; off > 0; off >>= 1) p += __shfl_xor(p, off, 64);
        if (lane == 0) w_out[e] = expf(p);
    }
}

// ---------------------------------------------------------------- gather-aggregate:
// one wave per dst node: aggN[n] = (sum_e w[e]*[src_feat[src[e]] | efeat[e]]) / sum_e w[e]
__global__ __launch_bounds__(256) void gather_agg_kernel(
    const int* __restrict__ off, const int* __restrict__ list,
    const int* __restrict__ src, const float* __restrict__ w,
    const float* __restrict__ src_feat, const float* __restrict__ efeat,
    unsigned short* __restrict__ aggN, int N)
{
    int n = (blockIdx.x << 2) + (threadIdx.x >> 6);
    if (n >= N) return;
    int lane = threadIdx.x & 63;
    int b = off[n], en = off[n + 1];
    float acc1 = 0.f, acc2 = 0.f, ws = 0.f;
    int i = b;
    int eN = 0, siN = 0; float wN = 0.f;
    if (i < en) { eN = list[i]; siN = src[eN]; wN = w[eN]; }
    while (i < en) {
        int e = eN, si = siN; float wi = wN;
        ++i;
        if (i < en) { eN = list[i]; siN = src[eN]; wN = w[eN]; }
        acc1 += wi * src_feat[(size_t)si * 64 + lane];
        acc2 += wi * efeat[(size_t)e * 64 + lane];
        ws += wi;
    }
    float sc = (ws > 0.f) ? 1.0f / ws : 0.f;
    aggN[(size_t)n * 128 + lane] = f2bf(acc1 * sc);
    aggN[(size_t)n * 128 + 64 + lane] = f2bf(acc2 * sc);
}

// ---------------------------------------------------------------- node post:
// [64 nodes/block] aggN(bf16,normalized)@Ww (K=128, N=32) + b -> out cols 32..63
__global__ __launch_bounds__(256) void node_post_kernel(
    const unsigned short* __restrict__ aggN, int N,
    const unsigned short* __restrict__ WT,   // [32][128] bf16 (c-major)
    const float* __restrict__ bias,          // [32]
    float* __restrict__ outp)                // rows stride 64, offset +32
{
    __shared__ unsigned short lA[64 * 128];
    __shared__ unsigned short lW[32 * 128];
    int tid = threadIdx.x;
    int n0 = blockIdx.x * 64;

    const uint4* wsrc = (const uint4*)WT;
    for (int i = tid; i < 32 * 16; i += 256) {
        int r = i >> 4, ch = i & 15;
        *(uint4*)&lW[r * 128 + ((ch ^ (r & 7)) << 3)] = wsrc[i];
    }
    for (int i = tid; i < 64 * 16; i += 256) {
        int r = i >> 4, ch = i & 15;
        int n = n0 + r;
        uint4 v = make_uint4(0u, 0u, 0u, 0u);
        if (n < N) v = *(const uint4*)&aggN[(size_t)n * 128 + ch * 8];
        *(uint4*)&lA[r * 128 + ((ch ^ (r & 7)) << 3)] = v;
    }
    __syncthreads();

    int wv = tid >> 6, lane = tid & 63;
    int r0 = wv * 16;
    int lrow = lane & 15, lkg = lane >> 4;
    int rr = r0 + lrow;

    bf16x8 a[4];
    #pragma unroll
    for (int kk = 0; kk < 4; ++kk) {
        int ch = kk * 4 + lkg;
        a[kk] = *(const bf16x8*)&lA[rr * 128 + ((ch ^ (rr & 7)) << 3)];
    }
    f32x4 acc[2];
    acc[0] = (f32x4){0.f, 0.f, 0.f, 0.f};
    acc[1] = (f32x4){0.f, 0.f, 0.f, 0.f};
    #pragma unroll
    for (int t = 0; t < 2; ++t) {
        int row = t * 16 + lrow;
        #pragma unroll
        for (int kk = 0; kk < 4; ++kk) {
            int ch = kk * 4 + lkg;
            bf16x8 b = *(const bf16x8*)&lW[row * 128 + ((ch ^ (row & 7)) << 3)];
            acc[t] = __builtin_amdgcn_mfma_f32_16x16x32_bf16(a[kk], b, acc[t], 0, 0, 0);
        }
    }
    #pragma unroll
    for (int t = 0; t < 2; ++t) {
        #pragma unroll
        for (int q = 0; q < 4; ++q) {
            int n = n0 + r0 + lkg * 4 + q;
            if (n >= N) continue;
            int c = t * 16 + lrow;
            outp[(size_t)n * 64 + 32 + c] = acc[t][q] + bias[c];
        }
    }
}

// ---------------------------------------------------------------- launch
extern "C" void kernel_launch(void* const* d_in, const int* in_sizes, int n_in,
                              void* d_out, int out_size, void* d_ws, size_t ws_size,
                              hipStream_t stream)
{
    const float* f_feat = (const float*)d_in[0];
    const float* b_feat = (const float*)d_in[1];
    const float* u_feat = (const float*)d_in[2];
    const float* v_feat = (const float*)d_in[3];
    const int* fsrc = (const int*)d_in[4];
    const int* fdst = (const int*)d_in[5];
    const int* bsrc = (const int*)d_in[6];
    const int* bdst = (const int*)d_in[7];
    const float* We  = (const float*)d_in[8];
    const float* be  = (const float*)d_in[9];
    const float* Wul = (const float*)d_in[10];
    const float* bul = (const float*)d_in[11];
    const float* Wvl = (const float*)d_in[12];
    const float* bvl = (const float*)d_in[13];
    const float* Wau = (const float*)d_in[14];
    const float* bau = (const float*)d_in[15];
    const float* Wav = (const float*)d_in[16];
    const float* bav = (const float*)d_in[17];
    const float* Wwu = (const float*)d_in[18];
    const float* bwu = (const float*)d_in[19];
    const float* Wwv = (const float*)d_in[20];
    const float* bwv = (const float*)d_in[21];
    const float* WVu = (const float*)d_in[22];
    const float* bVu = (const float*)d_in[23];
    const float* WVv = (const float*)d_in[24];
    const float* bVv = (const float*)d_in[25];

    int EF = in_sizes[0] / 64;
    int EB = in_sizes[1] / 64;
    int NU = in_sizes[2] / 64;
    int NV = in_sizes[3] / 64;

    float* out = (float*)d_out;
    float* hf = out;
    float* hb = hf + (size_t)EF * 64;
    float* hu = hb + (size_t)EB * 64;
    float* hv = hu + (size_t)NU * 64;

    char* wp = (char*)d_ws;
    auto alloc = [&](size_t bytes) { char* p = wp; wp += (bytes + 255) & ~(size_t)255; return p; };
    unsigned short* he_u  = (unsigned short*)alloc((size_t)NU * 64 * 2);
    unsigned short* he_v  = (unsigned short*)alloc((size_t)NV * 64 * 2);
    unsigned short* att_u = (unsigned short*)alloc((size_t)NU * 128 * 2);
    unsigned short* att_v = (unsigned short*)alloc((size_t)NV * 128 * 2);
    unsigned short* aggN_u = (unsigned short*)alloc((size_t)NU * 128 * 2);
    unsigned short* aggN_v = (unsigned short*)alloc((size_t)NV * 128 * 2);
    float* w_f = (float*)alloc((size_t)EF * 4);
    float* w_b = (float*)alloc((size_t)EB * 4);
    int* cnt_u = (int*)alloc((size_t)NU * 4);
    int* cnt_v = (int*)alloc((size_t)NV * 4);
    int* off_u = (int*)alloc((size_t)(NU + 1) * 4);
    int* off_v = (int*)alloc((size_t)(NV + 1) * 4);
    int* slot_f = (int*)alloc((size_t)EF * 4);
    int* slot_b = (int*)alloc((size_t)EB * 4);
    int* list_f = (int*)alloc((size_t)EF * 4);
    int* list_b = (int*)alloc((size_t)EB * 4);
    unsigned short* WeT  = (unsigned short*)alloc(64 * 64 * 2);
    unsigned short* WuT  = (unsigned short*)alloc(224 * 64 * 2);
    unsigned short* WvT  = (unsigned short*)alloc(224 * 64 * 2);
    unsigned short* WwuT = (unsigned short*)alloc(32 * 128 * 2);
    unsigned short* WwvT = (unsigned short*)alloc(32 * 128 * 2);
    float* bcu = (float*)alloc(224 * 4);
    float* bcv = (float*)alloc(224 * 4);

    prep_kernel<<<64, 256, 0, stream>>>(We, Wul, Wau, WVu, Wvl, Wav, WVv, Wwu, Wwv,
                                        bul, bau, bVu, bvl, bav, bVv,
                                        WeT, WuT, WvT, WwuT, WwvT, bcu, bcv,
                                        cnt_u, NU, cnt_v, NV);
    // CSR build (forward edges keyed by fdst -> v nodes; backward by bdst -> u nodes)
    count_kernel<<<1024, 256, 0, stream>>>(fdst, EF, cnt_v, slot_f);
    count_kernel<<<1024, 256, 0, stream>>>(bdst, EB, cnt_u, slot_b);
    scan_kernel<<<1, 1024, 0, stream>>>(cnt_v, NV, off_v);
    scan_kernel<<<1, 1024, 0, stream>>>(cnt_u, NU, off_u);
    scatter_kernel<<<1024, 256, 0, stream>>>(fdst, slot_f, off_v, EF, list_f);
    scatter_kernel<<<1024, 256, 0, stream>>>(bdst, slot_b, off_u, EB, list_b);

    node_pre_kernel<<<(NU + 63) / 64, 256, 0, stream>>>(u_feat, NU, WuT, bcu, he_u, att_u, hu);
    node_pre_kernel<<<(NV + 63) / 64, 256, 0, stream>>>(v_feat, NV, WvT, bcv, he_v, att_v, hv);

    edge_kernel<<<(EF + 63) / 64, 256, 0, stream>>>(f_feat, EF, fsrc, fdst, u_feat,
                                                    he_u, he_v, att_v, WeT, be, hf, w_f);
    edge_kernel<<<(EB + 63) / 64, 256, 0, stream>>>(b_feat, EB, bsrc, bdst, v_feat,
                                                    he_v, he_u, att_u, WeT, be, hb, w_b);

    gather_agg_kernel<<<(NV + 3) / 4, 256, 0, stream>>>(off_v, list_f, fsrc, w_f,
                                                        u_feat, f_feat, aggN_v, NV);
    gather_agg_kernel<<<(NU + 3) / 4, 256, 0, stream>>>(off_u, list_b, bsrc, w_b,
                                                        v_feat, b_feat, aggN_u, NU);

    node_post_kernel<<<(NU + 63) / 64, 256, 0, stream>>>(aggN_u, NU, WwuT, bwu, hu);
    node_post_kernel<<<(NV + 63) / 64, 256, 0, stream>>>(aggN_v, NV, WwvT, bwv, hv);
}

// Round 3
// 559.895 us; speedup vs baseline: 1.6572x; 1.6572x over previous
//
#include <hip/hip_runtime.h>
#include <hip/hip_bf16.h>
#include <cstdint>

typedef __attribute__((ext_vector_type(4))) float f32x4;
typedef __attribute__((ext_vector_type(8))) short bf16x8;

__device__ inline unsigned short f2bf(float f) {
    union { float f; unsigned u; } v; v.f = f;
    unsigned r = v.u + 0x7FFFu + ((v.u >> 16) & 1u);
    return (unsigned short)(r >> 16);
}
__device__ inline float bf2f(unsigned short h) {
    union { unsigned u; float f; } v; v.u = ((unsigned)h) << 16;
    return v.f;
}

// ---------------------------------------------------------------- prep
__global__ void prep_kernel(
    const float* __restrict__ We,
    const float* __restrict__ Wul, const float* __restrict__ Wau, const float* __restrict__ WVu,
    const float* __restrict__ Wvl, const float* __restrict__ Wav, const float* __restrict__ WVv,
    const float* __restrict__ Wwu, const float* __restrict__ Wwv,
    const float* __restrict__ bul, const float* __restrict__ bau, const float* __restrict__ bVu,
    const float* __restrict__ bvl, const float* __restrict__ bav, const float* __restrict__ bVv,
    unsigned short* __restrict__ WeT, unsigned short* __restrict__ WuT, unsigned short* __restrict__ WvT,
    unsigned short* __restrict__ WwuT, unsigned short* __restrict__ WwvT,
    float* __restrict__ bcu, float* __restrict__ bcv,
    int* __restrict__ cnt, int NTOT, int* __restrict__ off, int ETOT)
{
    int tid0 = blockIdx.x * blockDim.x + threadIdx.x;
    int stride = gridDim.x * blockDim.x;
    for (int i = tid0; i < 64 * 64; i += stride) { int c = i >> 6, k = i & 63; WeT[i] = f2bf(We[k * 64 + c]); }
    for (int i = tid0; i < 224 * 64; i += stride) {
        int c = i >> 6, k = i & 63;
        float v = (c < 64) ? Wul[k * 64 + c] : (c < 192) ? Wau[k * 128 + (c - 64)] : WVu[k * 32 + (c - 192)];
        WuT[i] = f2bf(v);
    }
    for (int i = tid0; i < 224 * 64; i += stride) {
        int c = i >> 6, k = i & 63;
        float v = (c < 64) ? Wvl[k * 64 + c] : (c < 192) ? Wav[k * 128 + (c - 64)] : WVv[k * 32 + (c - 192)];
        WvT[i] = f2bf(v);
    }
    for (int i = tid0; i < 32 * 128; i += stride) { int c = i >> 7, k = i & 127; WwuT[i] = f2bf(Wwu[k * 32 + c]); }
    for (int i = tid0; i < 32 * 128; i += stride) { int c = i >> 7, k = i & 127; WwvT[i] = f2bf(Wwv[k * 32 + c]); }
    for (int i = tid0; i < 224; i += stride) {
        bcu[i] = (i < 64) ? bul[i] : (i < 192) ? bau[i - 64] : bVu[i - 192];
        bcv[i] = (i < 64) ? bvl[i] : (i < 192) ? bav[i - 64] : bVv[i - 192];
    }
    for (int i = tid0; i < NTOT; i += stride) cnt[i] = 0;
    if (tid0 == 0) off[NTOT] = ETOT;
}

// ---------------------------------------------------------------- CSR build
// combined: u-nodes (dst of backward edges) occupy cnt[0..NU), v-nodes cnt[NU..NU+NV)
__global__ void count_kernel(const int* __restrict__ bdst, int EB,
                             const int* __restrict__ fdst, int EF, int NU,
                             int* __restrict__ cnt, int* __restrict__ slot)
{
    int i = blockIdx.x * blockDim.x + threadIdx.x;
    int stride = gridDim.x * blockDim.x;
    int ET = EB + EF;
    for (; i < ET; i += stride) {
        int d = (i < EB) ? bdst[i] : (NU + fdst[i - EB]);
        slot[i] = atomicAdd(&cnt[d], 1);
    }
}

__global__ __launch_bounds__(256) void scan_p1(const int* __restrict__ cnt, int n,
                                               int* __restrict__ bsum)
{
    __shared__ int red[256];
    int t = threadIdx.x;
    int idx = blockIdx.x * 1024 + t * 4;
    int s = 0;
    if (idx + 3 < n) {
        s = cnt[idx] + cnt[idx + 1] + cnt[idx + 2] + cnt[idx + 3];
    } else {
        for (int k = 0; k < 4; ++k) if (idx + k < n) s += cnt[idx + k];
    }
    red[t] = s;
    __syncthreads();
    for (int d = 128; d > 0; d >>= 1) {
        if (t < d) red[t] += red[t + d];
        __syncthreads();
    }
    if (t == 0) bsum[blockIdx.x] = red[0];
}

__global__ __launch_bounds__(512) void scan_p2(int* __restrict__ bsum, int nb)
{
    __shared__ int sc[512];
    int t = threadIdx.x;
    int s = (t < nb) ? bsum[t] : 0;
    sc[t] = s;
    __syncthreads();
    for (int d = 1; d < 512; d <<= 1) {
        int a = (t >= d) ? sc[t - d] : 0;
        __syncthreads();
        sc[t] += a;
        __syncthreads();
    }
    if (t < nb) bsum[t] = sc[t] - s;   // exclusive
}

__global__ __launch_bounds__(256) void scan_p3(const int* __restrict__ cnt, int n,
                                               const int* __restrict__ bsum,
                                               int* __restrict__ off)
{
    __shared__ int sc[256];
    int t = threadIdx.x;
    int idx = blockIdx.x * 1024 + t * 4;
    int v0 = 0, v1 = 0, v2 = 0, v3 = 0;
    if (idx + 3 < n) {
        v0 = cnt[idx]; v1 = cnt[idx + 1]; v2 = cnt[idx + 2]; v3 = cnt[idx + 3];
    } else {
        if (idx < n) v0 = cnt[idx];
        if (idx + 1 < n) v1 = cnt[idx + 1];
        if (idx + 2 < n) v2 = cnt[idx + 2];
        if (idx + 3 < n) v3 = cnt[idx + 3];
    }
    int s = v0 + v1 + v2 + v3;
    sc[t] = s;
    __syncthreads();
    for (int d = 1; d < 256; d <<= 1) {
        int a = (t >= d) ? sc[t - d] : 0;
        __syncthreads();
        sc[t] += a;
        __syncthreads();
    }
    int base = bsum[blockIdx.x] + sc[t] - s;
    if (idx < n) off[idx] = base; base += v0;
    if (idx + 1 < n) off[idx + 1] = base; base += v1;
    if (idx + 2 < n) off[idx + 2] = base; base += v2;
    if (idx + 3 < n) off[idx + 3] = base;
}

__global__ void scatter_kernel(const int* __restrict__ bdst, int EB,
                               const int* __restrict__ fdst, int EF, int NU,
                               const int* __restrict__ slot, const int* __restrict__ off,
                               int* __restrict__ list)
{
    int i = blockIdx.x * blockDim.x + threadIdx.x;
    int stride = gridDim.x * blockDim.x;
    int ET = EB + EF;
    for (; i < ET; i += stride) {
        if (i < EB) list[off[bdst[i]] + slot[i]] = i;
        else        list[off[NU + fdst[i - EB]] + slot[i]] = i - EB;
    }
}

// ---------------------------------------------------------------- node pre:
// [64 nodes/block] feat@[Wl|Wa|WV] (K=64, N=224) -> he(bf16), att(bf16), outV(f32)
__global__ __launch_bounds__(256) void node_pre_kernel(
    const float* __restrict__ feat, int N,
    const unsigned short* __restrict__ WT,   // [224][64] bf16 (c-major)
    const float* __restrict__ bcat,          // [224]
    unsigned short* __restrict__ he,         // [N][64]  bf16
    unsigned short* __restrict__ att,        // [N][128] bf16
    float* __restrict__ outV)                // out rows stride 64, cols 0..31
{
    __shared__ unsigned short lA[64 * 64];
    __shared__ unsigned short lW[224 * 64];
    int tid = threadIdx.x;
    int n0 = blockIdx.x * 64;

    const uint4* wsrc = (const uint4*)WT;
    for (int i = tid; i < 224 * 8; i += 256) {
        int r = i >> 3, ch = i & 7;
        *(uint4*)&lW[r * 64 + ((ch ^ (r & 7)) << 3)] = wsrc[i];
    }
    #pragma unroll
    for (int j = 0; j < 4; ++j) {
        int fi = j * 1024 + tid * 4;
        int r = fi >> 6, k = fi & 63;
        int n = n0 + r;
        float4 v = make_float4(0.f, 0.f, 0.f, 0.f);
        if (n < N) v = *(const float4*)&feat[(size_t)n * 64 + k];
        uint2 pk;
        pk.x = (unsigned)f2bf(v.x) | ((unsigned)f2bf(v.y) << 16);
        pk.y = (unsigned)f2bf(v.z) | ((unsigned)f2bf(v.w) << 16);
        *(uint2*)&lA[r * 64 + (((k >> 3) ^ (r & 7)) << 3) + (k & 7)] = pk;
    }
    __syncthreads();

    int wv = tid >> 6, lane = tid & 63;
    int r0 = wv * 16;
    int lrow = lane & 15, lkg = lane >> 4;
    int rr = r0 + lrow;

    bf16x8 a[2];
    #pragma unroll
    for (int h = 0; h < 2; ++h) {
        int ch = h * 4 + lkg;
        a[h] = *(const bf16x8*)&lA[rr * 64 + ((ch ^ (rr & 7)) << 3)];
    }
    f32x4 acc[14];
    #pragma unroll
    for (int t = 0; t < 14; ++t) acc[t] = (f32x4){0.f, 0.f, 0.f, 0.f};
    #pragma unroll
    for (int t = 0; t < 14; ++t) {
        int row = t * 16 + lrow;
        #pragma unroll
        for (int h = 0; h < 2; ++h) {
            int ch = h * 4 + lkg;
            bf16x8 b = *(const bf16x8*)&lW[row * 64 + ((ch ^ (row & 7)) << 3)];
            acc[t] = __builtin_amdgcn_mfma_f32_16x16x32_bf16(a[h], b, acc[t], 0, 0, 0);
        }
    }
    #pragma unroll
    for (int t = 0; t < 14; ++t) {
        #pragma unroll
        for (int q = 0; q < 4; ++q) {
            int n = n0 + r0 + lkg * 4 + q;
            if (n >= N) continue;
            int c = t * 16 + lrow;
            float v = acc[t][q] + bcat[c];
            if (t < 4)       he[(size_t)n * 64 + c] = f2bf(v);
            else if (t < 12) att[(size_t)n * 128 + (c - 64)] = f2bf(v);
            else             outV[(size_t)n * 64 + (c - 192)] = v;
        }
    }
}

// ---------------------------------------------------------------- edge:
// [64 edges/block] out_he = e@We + be + he_src[src] + he_dst[dst]  (pure GEMM + epilogue)
__global__ __launch_bounds__(256) void edge_kernel(
    const float* __restrict__ efeat, int E,
    const int* __restrict__ src, const int* __restrict__ dst,
    const unsigned short* __restrict__ he_src, const unsigned short* __restrict__ he_dst,
    const unsigned short* __restrict__ WeT,
    const float* __restrict__ be,
    float* __restrict__ out_he)
{
    // 16 KB: lA(8K)+lW(8K) during MFMA, reused as sAcc(16K f32) after
    __shared__ __align__(16) char smem[16384];
    unsigned short* lA = (unsigned short*)smem;
    unsigned short* lW = (unsigned short*)(smem + 8192);
    float* sAcc = (float*)smem;

    int tid = threadIdx.x;
    int e0 = blockIdx.x * 64;

    const uint4* wsrc = (const uint4*)WeT;
    for (int i = tid; i < 512; i += 256) {
        int r = i >> 3, ch = i & 7;
        *(uint4*)&lW[r * 64 + ((ch ^ (r & 7)) << 3)] = wsrc[i];
    }
    #pragma unroll
    for (int j = 0; j < 4; ++j) {
        int fi = j * 1024 + tid * 4;
        int r = fi >> 6, k = fi & 63;
        int e = e0 + r;
        float4 v = make_float4(0.f, 0.f, 0.f, 0.f);
        if (e < E) v = *(const float4*)&efeat[(size_t)e * 64 + k];
        uint2 pk;
        pk.x = (unsigned)f2bf(v.x) | ((unsigned)f2bf(v.y) << 16);
        pk.y = (unsigned)f2bf(v.z) | ((unsigned)f2bf(v.w) << 16);
        *(uint2*)&lA[r * 64 + (((k >> 3) ^ (r & 7)) << 3) + (k & 7)] = pk;
    }
    __syncthreads();

    int wv = tid >> 6, lane = tid & 63;
    int r0 = wv * 16;
    int lrow = lane & 15, lkg = lane >> 4;
    int rr = r0 + lrow;

    bf16x8 a[2];
    #pragma unroll
    for (int h = 0; h < 2; ++h) {
        int ch = h * 4 + lkg;
        a[h] = *(const bf16x8*)&lA[rr * 64 + ((ch ^ (rr & 7)) << 3)];
    }
    f32x4 acc[4];
    #pragma unroll
    for (int t = 0; t < 4; ++t) acc[t] = (f32x4){0.f, 0.f, 0.f, 0.f};
    #pragma unroll
    for (int t = 0; t < 4; ++t) {
        int row = t * 16 + lrow;
        #pragma unroll
        for (int h = 0; h < 2; ++h) {
            int ch = h * 4 + lkg;
            bf16x8 b = *(const bf16x8*)&lW[row * 64 + ((ch ^ (row & 7)) << 3)];
            acc[t] = __builtin_amdgcn_mfma_f32_16x16x32_bf16(a[h], b, acc[t], 0, 0, 0);
        }
    }
    __syncthreads();   // all waves done reading lA/lW
    #pragma unroll
    for (int t = 0; t < 4; ++t) {
        #pragma unroll
        for (int q = 0; q < 4; ++q) {
            int r = r0 + lkg * 4 + q;
            int c = t * 16 + lrow;
            sAcc[r * 64 + c] = acc[t][q] + be[c];
        }
    }
    __syncthreads();

    // epilogue: coalesced row access per edge
    for (int q2 = 0; q2 < 16; ++q2) {
        int rloc = wv * 16 + q2;
        int e = e0 + rloc;
        if (e >= E) break;
        int si = src[e], di = dst[e];
        int c = lane;
        float hs = bf2f(he_src[(size_t)si * 64 + c]);
        float hd = bf2f(he_dst[(size_t)di * 64 + c]);
        out_he[(size_t)e * 64 + c] = sAcc[rloc * 64 + c] + hs + hd;
    }
}

// ---------------------------------------------------------------- gather-aggregate:
// one wave per dst node; fused score+softmax+agg+normalize.
// segment g<NU: u nodes (backward edges); else v nodes (forward edges)
__global__ __launch_bounds__(256) void gather_agg_kernel(
    const int* __restrict__ off, const int* __restrict__ list,
    const int* __restrict__ bsrc, const int* __restrict__ fsrc,
    const float* __restrict__ u_feat, const float* __restrict__ v_feat,
    const float* __restrict__ f_feat, const float* __restrict__ b_feat,
    const unsigned short* __restrict__ att_u, const unsigned short* __restrict__ att_v,
    unsigned short* __restrict__ aggN_u, unsigned short* __restrict__ aggN_v,
    int NU, int NT)
{
    int g = (blockIdx.x << 2) + (threadIdx.x >> 6);
    if (g >= NT) return;
    int lane = threadIdx.x & 63;

    const int* src; const float* sfeat; const float* ef;
    const unsigned short* att; unsigned short* outp; int n;
    if (g < NU) { n = g;      src = bsrc; sfeat = v_feat; ef = b_feat; att = att_u; outp = aggN_u; }
    else        { n = g - NU; src = fsrc; sfeat = u_feat; ef = f_feat; att = att_v; outp = aggN_v; }

    float t1 = bf2f(att[(size_t)n * 128 + lane]);
    float t2 = bf2f(att[(size_t)n * 128 + 64 + lane]);
    int b = off[g], en = off[g + 1];
    float acc1 = 0.f, acc2 = 0.f, ws = 0.f;

    int eN = 0, siN = 0;
    if (b < en) { eN = list[b]; siN = src[eN]; }
    for (int i = b; i < en; ++i) {
        int e = eN, si = siN;
        if (i + 1 < en) { eN = list[i + 1]; siN = src[eN]; }
        float a1 = sfeat[(size_t)si * 64 + lane];
        float a2 = ef[(size_t)e * 64 + lane];
        float p = a1 * t1 + a2 * t2;
        #pragma unroll
        for (int o = 32; o > 0; o >>= 1) p += __shfl_xor(p, o, 64);
        float w = expf(p);
        acc1 += w * a1;
        acc2 += w * a2;
        ws += w;
    }
    float sc = (ws > 0.f) ? 1.0f / ws : 0.f;
    outp[(size_t)n * 128 + lane] = f2bf(acc1 * sc);
    outp[(size_t)n * 128 + 64 + lane] = f2bf(acc2 * sc);
}

// ---------------------------------------------------------------- node post:
// [64 nodes/block] aggN(bf16,normalized)@Ww (K=128, N=32) + b -> out cols 32..63
__global__ __launch_bounds__(256) void node_post_kernel(
    const unsigned short* __restrict__ aggN, int N,
    const unsigned short* __restrict__ WT,   // [32][128] bf16 (c-major)
    const float* __restrict__ bias,          // [32]
    float* __restrict__ outp)                // rows stride 64, offset +32
{
    __shared__ unsigned short lA[64 * 128];
    __shared__ unsigned short lW[32 * 128];
    int tid = threadIdx.x;
    int n0 = blockIdx.x * 64;

    const uint4* wsrc = (const uint4*)WT;
    for (int i = tid; i < 32 * 16; i += 256) {
        int r = i >> 4, ch = i & 15;
        *(uint4*)&lW[r * 128 + ((ch ^ (r & 7)) << 3)] = wsrc[i];
    }
    for (int i = tid; i < 64 * 16; i += 256) {
        int r = i >> 4, ch = i & 15;
        int n = n0 + r;
        uint4 v = make_uint4(0u, 0u, 0u, 0u);
        if (n < N) v = *(const uint4*)&aggN[(size_t)n * 128 + ch * 8];
        *(uint4*)&lA[r * 128 + ((ch ^ (r & 7)) << 3)] = v;
    }
    __syncthreads();

    int wv = tid >> 6, lane = tid & 63;
    int r0 = wv * 16;
    int lrow = lane & 15, lkg = lane >> 4;
    int rr = r0 + lrow;

    bf16x8 a[4];
    #pragma unroll
    for (int kk = 0; kk < 4; ++kk) {
        int ch = kk * 4 + lkg;
        a[kk] = *(const bf16x8*)&lA[rr * 128 + ((ch ^ (rr & 7)) << 3)];
    }
    f32x4 acc[2];
    acc[0] = (f32x4){0.f, 0.f, 0.f, 0.f};
    acc[1] = (f32x4){0.f, 0.f, 0.f, 0.f};
    #pragma unroll
    for (int t = 0; t < 2; ++t) {
        int row = t * 16 + lrow;
        #pragma unroll
        for (int kk = 0; kk < 4; ++kk) {
            int ch = kk * 4 + lkg;
            bf16x8 b = *(const bf16x8*)&lW[row * 128 + ((ch ^ (row & 7)) << 3)];
            acc[t] = __builtin_amdgcn_mfma_f32_16x16x32_bf16(a[kk], b, acc[t], 0, 0, 0);
        }
    }
    #pragma unroll
    for (int t = 0; t < 2; ++t) {
        #pragma unroll
        for (int q = 0; q < 4; ++q) {
            int n = n0 + r0 + lkg * 4 + q;
            if (n >= N) continue;
            int c = t * 16 + lrow;
            outp[(size_t)n * 64 + 32 + c] = acc[t][q] + bias[c];
        }
    }
}

// ---------------------------------------------------------------- launch
extern "C" void kernel_launch(void* const* d_in, const int* in_sizes, int n_in,
                              void* d_out, int out_size, void* d_ws, size_t ws_size,
                              hipStream_t stream)
{
    const float* f_feat = (const float*)d_in[0];
    const float* b_feat = (const float*)d_in[1];
    const float* u_feat = (const float*)d_in[2];
    const float* v_feat = (const float*)d_in[3];
    const int* fsrc = (const int*)d_in[4];
    const int* fdst = (const int*)d_in[5];
    const int* bsrc = (const int*)d_in[6];
    const int* bdst = (const int*)d_in[7];
    const float* We  = (const float*)d_in[8];
    const float* be  = (const float*)d_in[9];
    const float* Wul = (const float*)d_in[10];
    const float* bul = (const float*)d_in[11];
    const float* Wvl = (const float*)d_in[12];
    const float* bvl = (const float*)d_in[13];
    const float* Wau = (const float*)d_in[14];
    const float* bau = (const float*)d_in[15];
    const float* Wav = (const float*)d_in[16];
    const float* bav = (const float*)d_in[17];
    const float* Wwu = (const float*)d_in[18];
    const float* bwu = (const float*)d_in[19];
    const float* Wwv = (const float*)d_in[20];
    const float* bwv = (const float*)d_in[21];
    const float* WVu = (const float*)d_in[22];
    const float* bVu = (const float*)d_in[23];
    const float* WVv = (const float*)d_in[24];
    const float* bVv = (const float*)d_in[25];

    int EF = in_sizes[0] / 64;
    int EB = in_sizes[1] / 64;
    int NU = in_sizes[2] / 64;
    int NV = in_sizes[3] / 64;
    int NTOT = NU + NV;
    int ETOT = EB + EF;
    int NB = (NTOT + 1023) / 1024;   // scan blocks (<=512 required)

    float* out = (float*)d_out;
    float* hf = out;
    float* hb = hf + (size_t)EF * 64;
    float* hu = hb + (size_t)EB * 64;
    float* hv = hu + (size_t)NU * 64;

    char* wp = (char*)d_ws;
    auto alloc = [&](size_t bytes) { char* p = wp; wp += (bytes + 255) & ~(size_t)255; return p; };
    unsigned short* he_u  = (unsigned short*)alloc((size_t)NU * 64 * 2);
    unsigned short* he_v  = (unsigned short*)alloc((size_t)NV * 64 * 2);
    unsigned short* att_u = (unsigned short*)alloc((size_t)NU * 128 * 2);
    unsigned short* att_v = (unsigned short*)alloc((size_t)NV * 128 * 2);
    unsigned short* aggN_u = (unsigned short*)alloc((size_t)NU * 128 * 2);
    unsigned short* aggN_v = (unsigned short*)alloc((size_t)NV * 128 * 2);
    int* cnt  = (int*)alloc((size_t)NTOT * 4);
    int* off  = (int*)alloc((size_t)(NTOT + 1) * 4);
    int* slot = (int*)alloc((size_t)ETOT * 4);
    int* list = (int*)alloc((size_t)ETOT * 4);
    int* bsum = (int*)alloc((size_t)(NB > 512 ? NB : 512) * 4);
    unsigned short* WeT  = (unsigned short*)alloc(64 * 64 * 2);
    unsigned short* WuT  = (unsigned short*)alloc(224 * 64 * 2);
    unsigned short* WvT  = (unsigned short*)alloc(224 * 64 * 2);
    unsigned short* WwuT = (unsigned short*)alloc(32 * 128 * 2);
    unsigned short* WwvT = (unsigned short*)alloc(32 * 128 * 2);
    float* bcu = (float*)alloc(224 * 4);
    float* bcv = (float*)alloc(224 * 4);

    prep_kernel<<<64, 256, 0, stream>>>(We, Wul, Wau, WVu, Wvl, Wav, WVv, Wwu, Wwv,
                                        bul, bau, bVu, bvl, bav, bVv,
                                        WeT, WuT, WvT, WwuT, WwvT, bcu, bcv,
                                        cnt, NTOT, off, ETOT);
    count_kernel<<<1024, 256, 0, stream>>>(bdst, EB, fdst, EF, NU, cnt, slot);
    scan_p1<<<NB, 256, 0, stream>>>(cnt, NTOT, bsum);
    scan_p2<<<1, 512, 0, stream>>>(bsum, NB);
    scan_p3<<<NB, 256, 0, stream>>>(cnt, NTOT, bsum, off);
    scatter_kernel<<<1024, 256, 0, stream>>>(bdst, EB, fdst, EF, NU, slot, off, list);

    node_pre_kernel<<<(NU + 63) / 64, 256, 0, stream>>>(u_feat, NU, WuT, bcu, he_u, att_u, hu);
    node_pre_kernel<<<(NV + 63) / 64, 256, 0, stream>>>(v_feat, NV, WvT, bcv, he_v, att_v, hv);

    edge_kernel<<<(EF + 63) / 64, 256, 0, stream>>>(f_feat, EF, fsrc, fdst, he_u, he_v, WeT, be, hf);
    edge_kernel<<<(EB + 63) / 64, 256, 0, stream>>>(b_feat, EB, bsrc, bdst, he_v, he_u, WeT, be, hb);

    gather_agg_kernel<<<(NTOT + 3) / 4, 256, 0, stream>>>(off, list, bsrc, fsrc,
                                                          u_feat, v_feat, f_feat, b_feat,
                                                          att_u, att_v, aggN_u, aggN_v, NU, NTOT);

    node_post_kernel<<<(NU + 63) / 64, 256, 0, stream>>>(aggN_u, NU, WwuT, bwu, hu);
    node_post_kernel<<<(NV + 63) / 64, 256, 0, stream>>>(aggN_v, NV, WwvT, bwv, hv);
}